// Round 11
// baseline (171.076 us; speedup 1.0000x reference)
//
#include <hip/hip_runtime.h>
#include <hip/hip_bf16.h>

typedef __attribute__((ext_vector_type(8))) short short8;
typedef __attribute__((ext_vector_type(4))) short s16x4;
typedef __attribute__((ext_vector_type(4))) float f32x4;

#define BATCH 524288
#define KD 512
#define OD 32
#define RPB 1024           // rows per block
#define NB1 (BATCH / RPB)  // 512 blocks = 2 blocks/CU resident
#define RPC 16             // rows per chunk
#define NCHUNK (RPB / RPC) // 64

__device__ __forceinline__ short bf16b(float f) {
  __hip_bfloat16 h = __float2bfloat16(f);
  return __builtin_bit_cast(short, h);
}
__device__ __forceinline__ s16x4 cvt4(f32x4 v) {
  s16x4 r;
  r[0] = bf16b(v[0]); r[1] = bf16b(v[1]);
  r[2] = bf16b(v[2]); r[3] = bf16b(v[3]);
  return r;
}
__device__ __forceinline__ short8 pack8(f32x4 a, f32x4 b) {
  short8 r;
  r[0] = bf16b(a[0]); r[1] = bf16b(a[1]); r[2] = bf16b(a[2]); r[3] = bf16b(a[3]);
  r[4] = bf16b(b[0]); r[5] = bf16b(b[1]); r[6] = bf16b(b[2]); r[7] = bf16b(b[3]);
  return r;
}
#define NTLOAD(p) __builtin_nontemporal_load(reinterpret_cast<const f32x4*>(p))

// K1: LDS-staged GEMM+LSE, combine-free. W fragments live in REGISTERS
// (loaded once from L2; no Wl, no scratch). Each wave computes the chunk's
// full K=512 redundantly (4x MFMA = ~22% pipe, free) -> no cross-wave
// combine, ONE barrier per chunk, LDS = 32 KB. Global reads stay
// memcpy-shaped (4 consecutive rows x 2 KB per wave per chunk).
__global__ __launch_bounds__(256, 2) void k1_gemm_lse(const float* __restrict__ x,
                                                      const float* __restrict__ W,
                                                      float* __restrict__ partial) {
  __shared__ __align__(16) short Xl[2][RPC * KD];  // 2 x 16 KB, swizzled

  const int tid = threadIdx.x;
  const int wave = tid >> 6;
  const int lane = tid & 63;
  const int l15 = lane & 15;
  const int grp = lane >> 4;  // 0..3
  const size_t blockRow = (size_t)blockIdx.x * RPB;

  // ---- W fragments -> registers (once; W is L2/L3-resident, 64 KB) ----
  // B[k][col] = W[col][k]; lane needs rows l15 and 16+l15, k = ks*32+grp*8..+8
  short8 wb0[16], wb1[16];
#pragma unroll
  for (int ks = 0; ks < 16; ++ks) {
    const float* wp0 = W + l15 * KD + ks * 32 + grp * 8;
    const float* wp1 = W + (16 + l15) * KD + ks * 32 + grp * 8;
    wb0[ks] = pack8(*reinterpret_cast<const f32x4*>(wp0),
                    *reinterpret_cast<const f32x4*>(wp0 + 4));
    wb1[ks] = pack8(*reinterpret_cast<const f32x4*>(wp1),
                    *reinterpret_cast<const f32x4*>(wp1 + 4));
  }

  f32x4 h0, h1, h2, h3, h4, h5, h6, h7;  // staged x (4 rows x 2 loads each)

  // ---- prologue: load + write chunk 0 ----
  {
    const float* gp = x + (blockRow + wave * 4) * KD + lane * 4;
    h0 = NTLOAD(gp);        h1 = NTLOAD(gp + 256);
    h2 = NTLOAD(gp + 512);  h3 = NTLOAD(gp + 768);
    h4 = NTLOAD(gp + 1024); h5 = NTLOAD(gp + 1280);
    h6 = NTLOAD(gp + 1536); h7 = NTLOAD(gp + 1792);
  }
#pragma unroll
  for (int m = 0; m < 8; ++m) {
    int r = wave * 4 + (m >> 1);
    int k = (m & 1) * 256 + lane * 4;
    int iw = (r * KD + k) ^ ((r & 7) << 3);  // 16B-granule XOR swizzle
    f32x4 hv = (m == 0) ? h0 : (m == 1) ? h1 : (m == 2) ? h2 : (m == 3) ? h3
             : (m == 4) ? h4 : (m == 5) ? h5 : (m == 6) ? h6 : h7;
    *reinterpret_cast<s16x4*>(&Xl[0][iw]) = cvt4(hv);
  }
  __syncthreads();

  float runM = -INFINITY, runS = 0.0f;

  for (int c = 0; c < NCHUNK; ++c) {
    const int p = c & 1;
    if (c < NCHUNK - 1) {  // issue next chunk's loads (fly under compute)
      const float* gp = x + (blockRow + (size_t)(c + 1) * RPC + wave * 4) * KD + lane * 4;
      h0 = NTLOAD(gp);        h1 = NTLOAD(gp + 256);
      h2 = NTLOAD(gp + 512);  h3 = NTLOAD(gp + 768);
      h4 = NTLOAD(gp + 1024); h5 = NTLOAD(gp + 1280);
      h6 = NTLOAD(gp + 1536); h7 = NTLOAD(gp + 1792);
    }
    // ---- full-K GEMM for this chunk (W from registers) ----
    f32x4 acc0 = {0.f, 0.f, 0.f, 0.f};
    f32x4 acc1 = {0.f, 0.f, 0.f, 0.f};
#pragma unroll
    for (int ks = 0; ks < 16; ++ks) {
      int ia = (l15 * KD + ks * 32 + grp * 8) ^ ((l15 & 7) << 3);
      short8 af = *reinterpret_cast<const short8*>(&Xl[p][ia]);
      acc0 = __builtin_amdgcn_mfma_f32_16x16x32_bf16(af, wb0[ks], acc0, 0, 0, 0);
      acc1 = __builtin_amdgcn_mfma_f32_16x16x32_bf16(af, wb1[ks], acc1, 0, 0, 0);
    }
    // ---- write next chunk's rows into the other buffer ----
    if (c < NCHUNK - 1) {
#pragma unroll
      for (int m = 0; m < 8; ++m) {
        int r = wave * 4 + (m >> 1);
        int k = (m & 1) * 256 + lane * 4;
        int iw = (r * KD + k) ^ ((r & 7) << 3);
        f32x4 hv = (m == 0) ? h0 : (m == 1) ? h1 : (m == 2) ? h2 : (m == 3) ? h3
                 : (m == 4) ? h4 : (m == 5) ? h5 : (m == 6) ? h6 : h7;
        *reinterpret_cast<s16x4*>(&Xl[p ^ 1][iw]) = cvt4(hv);
      }
    }
    // ---- rowmax + chunk LSE, online merge (overlaps barrier wait) ----
    // D layout: lane holds D[grp*4 + r][l15] (acc0: outs 0-15, acc1: 16-31)
    float v0 = fmaxf(acc0[0], acc1[0]);
    float v1 = fmaxf(acc0[1], acc1[1]);
    float v2 = fmaxf(acc0[2], acc1[2]);
    float v3 = fmaxf(acc0[3], acc1[3]);
#pragma unroll
    for (int mask = 1; mask < 16; mask <<= 1) {
      v0 = fmaxf(v0, __shfl_xor(v0, mask));
      v1 = fmaxf(v1, __shfl_xor(v1, mask));
      v2 = fmaxf(v2, __shfl_xor(v2, mask));
      v3 = fmaxf(v3, __shfl_xor(v3, mask));
    }
    float tmax = fmaxf(fmaxf(v0, v1), fmaxf(v2, v3));
    float wmax = fmaxf(tmax, __shfl_xor(tmax, 16));
    wmax = fmaxf(wmax, __shfl_xor(wmax, 32));
    float s = __expf(v0 - wmax) + __expf(v1 - wmax) +
              __expf(v2 - wmax) + __expf(v3 - wmax);
#pragma unroll
    for (int mask = 1; mask < 64; mask <<= 1) s += __shfl_xor(s, mask);
    s *= (1.0f / 16.0f);  // each row counted on its 16 l15 lanes
    float nM = fmaxf(runM, wmax);
    runS = runS * __expf(runM - nM) + s * __expf(wmax - nM);
    runM = nM;

    if (c < NCHUNK - 1) __syncthreads();  // one barrier per chunk
  }

  // all 4 waves hold bitwise-identical (runM, runS) over the block's rows
  if (tid == 0) {
    partial[2 * blockIdx.x] = runM;
    partial[2 * blockIdx.x + 1] = runS;
  }
}

// K2+K3 fused: each block redundantly reduces the 512 (max,sum) pairs
// (4 KB, L2/L3-resident) -> l2 scalar, then fills its 4 KB output slice.
__global__ __launch_bounds__(256) void k23_reduce_fill(const float* __restrict__ partial,
                                                       float* __restrict__ out) {
  const int tid = threadIdx.x;
  const int wave = tid >> 6;
  const int lane = tid & 63;
  float Ml[2], Sl[2];
  float m = -INFINITY;
#pragma unroll
  for (int j = 0; j < 2; ++j) {
    int i = tid + j * 256;
    Ml[j] = partial[2 * i];
    Sl[j] = partial[2 * i + 1];
    m = fmaxf(m, Ml[j]);
  }
#pragma unroll
  for (int mask = 1; mask < 64; mask <<= 1) m = fmaxf(m, __shfl_xor(m, mask));
  __shared__ float lm[4], lsum[4], vsh;
  if (lane == 0) lm[wave] = m;
  __syncthreads();
  float gM = fmaxf(fmaxf(lm[0], lm[1]), fmaxf(lm[2], lm[3]));
  float s = 0.0f;
#pragma unroll
  for (int j = 0; j < 2; ++j) s += Sl[j] * __expf(Ml[j] - gM);
#pragma unroll
  for (int mask = 1; mask < 64; mask <<= 1) s += __shfl_xor(s, mask);
  if (lane == 0) lsum[wave] = s;
  __syncthreads();
  if (tid == 0) {
    float S = lsum[0] + lsum[1] + lsum[2] + lsum[3];
    // l2 = l1 + log(B), B = 2^19
    vsh = gM + logf(S) + 19.0f * 0.69314718055994530942f;
  }
  __syncthreads();
  float v = vsh;
  size_t i = ((size_t)blockIdx.x * 256 + tid) * 4;
  f32x4 o = {v, v, v, v};
  *reinterpret_cast<f32x4*>(out + i) = o;
}

extern "C" void kernel_launch(void* const* d_in, const int* in_sizes, int n_in,
                              void* d_out, int out_size, void* d_ws, size_t ws_size,
                              hipStream_t stream) {
  const float* x = (const float*)d_in[0];
  const float* W = (const float*)d_in[1];
  float* out = (float*)d_out;
  float* ws = (float*)d_ws;

  k1_gemm_lse<<<NB1, 256, 0, stream>>>(x, W, ws);
  k23_reduce_fill<<<BATCH / 1024, 256, 0, stream>>>(ws, out);
}

// Round 13
// 164.788 us; speedup vs baseline: 1.0382x; 1.0382x over previous
//
#include <hip/hip_runtime.h>
#include <hip/hip_bf16.h>

typedef __attribute__((ext_vector_type(8))) short short8;
typedef __attribute__((ext_vector_type(4))) short s16x4;
typedef __attribute__((ext_vector_type(4))) float f32x4;

#define BATCH 524288
#define KD 512
#define OD 32
#define RPB 1024           // rows per block
#define NB1 (BATCH / RPB)  // 512 blocks = 2 blocks/CU resident
#define RPC 16             // rows per chunk
#define NCHUNK (RPB / RPC) // 64

__device__ __forceinline__ short bf16b(float f) {
  __hip_bfloat16 h = __float2bfloat16(f);
  return __builtin_bit_cast(short, h);
}
__device__ __forceinline__ s16x4 cvt4(f32x4 v) {
  s16x4 r;
  r[0] = bf16b(v[0]); r[1] = bf16b(v[1]);
  r[2] = bf16b(v[2]); r[3] = bf16b(v[3]);
  return r;
}
__device__ __forceinline__ short8 pack8(f32x4 a, f32x4 b) {
  short8 r;
  r[0] = bf16b(a[0]); r[1] = bf16b(a[1]); r[2] = bf16b(a[2]); r[3] = bf16b(a[3]);
  r[4] = bf16b(b[0]); r[5] = bf16b(b[1]); r[6] = bf16b(b[2]); r[7] = bf16b(b[3]);
  return r;
}
#define NTLOAD(p) __builtin_nontemporal_load(reinterpret_cast<const f32x4*>(p))

// K1: round-10 structure (LDS-staged memcpy-shaped reads, k-split-4 across
// waves, scratch combine) with two critical-path shaves:
//  (a) each wave's k-window W fragments in registers (32 VGPR) -> 4 ds_reads
//      per chunk instead of 12, no Wl in LDS;
//  (b) cross-lane LSE tree deferred to every 4th chunk (batched 64-row LSE,
//      rounds-3/4-validated math); per chunk only 4 fmax.
__global__ __launch_bounds__(256, 2) void k1_gemm_lse(const float* __restrict__ x,
                                                      const float* __restrict__ W,
                                                      float* __restrict__ partial) {
  __shared__ __align__(16) short Xl[2][RPC * KD];      // 2 x 16 KB, swizzled
  __shared__ __align__(16) float scratch[4 * 64 * 8];  // 8 KB

  const int tid = threadIdx.x;
  const int wave = tid >> 6;
  const int lane = tid & 63;
  const int l15 = lane & 15;
  const int grp = lane >> 4;  // 0..3
  const size_t blockRow = (size_t)blockIdx.x * RPB;
  const int kw = wave * 128;  // this wave's k-window

  // ---- my k-window's W fragments -> registers (L2-resident read) ----
  short8 wb0[4], wb1[4];
#pragma unroll
  for (int ks = 0; ks < 4; ++ks) {
    const float* wp0 = W + l15 * KD + kw + ks * 32 + grp * 8;
    const float* wp1 = W + (16 + l15) * KD + kw + ks * 32 + grp * 8;
    wb0[ks] = pack8(*reinterpret_cast<const f32x4*>(wp0),
                    *reinterpret_cast<const f32x4*>(wp0 + 4));
    wb1[ks] = pack8(*reinterpret_cast<const f32x4*>(wp1),
                    *reinterpret_cast<const f32x4*>(wp1 + 4));
  }

  f32x4 h0, h1, h2, h3, h4, h5, h6, h7;  // staged x (4 rows x 2 loads each)

  // ---- prologue: load + write chunk 0 ----
  {
    const float* gp = x + (blockRow + wave * 4) * KD + lane * 4;
    h0 = NTLOAD(gp);        h1 = NTLOAD(gp + 256);
    h2 = NTLOAD(gp + 512);  h3 = NTLOAD(gp + 768);
    h4 = NTLOAD(gp + 1024); h5 = NTLOAD(gp + 1280);
    h6 = NTLOAD(gp + 1536); h7 = NTLOAD(gp + 1792);
  }
#pragma unroll
  for (int m = 0; m < 8; ++m) {
    int r = wave * 4 + (m >> 1);
    int k = (m & 1) * 256 + lane * 4;
    int iw = (r * KD + k) ^ ((r & 7) << 3);  // 16B-granule XOR swizzle
    f32x4 hv = (m == 0) ? h0 : (m == 1) ? h1 : (m == 2) ? h2 : (m == 3) ? h3
             : (m == 4) ? h4 : (m == 5) ? h5 : (m == 6) ? h6 : h7;
    *reinterpret_cast<s16x4*>(&Xl[0][iw]) = cvt4(hv);
  }
  __syncthreads();

  float runM = -INFINITY, runS = 0.0f;

  for (int cb = 0; cb < NCHUNK / 4; ++cb) {
    float v[4][4];  // [q][r], q static via unrolled loop (rule #20 safe)
#pragma unroll
    for (int q = 0; q < 4; ++q) {
      const int c = cb * 4 + q;
      const int p = q & 1;  // cb*4 is even -> parity = q&1, compile-time
      if (c < NCHUNK - 1) {  // issue next chunk's loads (fly under compute)
        const float* gp = x + (blockRow + (size_t)(c + 1) * RPC + wave * 4) * KD + lane * 4;
        h0 = NTLOAD(gp);        h1 = NTLOAD(gp + 256);
        h2 = NTLOAD(gp + 512);  h3 = NTLOAD(gp + 768);
        h4 = NTLOAD(gp + 1024); h5 = NTLOAD(gp + 1280);
        h6 = NTLOAD(gp + 1536); h7 = NTLOAD(gp + 1792);
      }
      // ---- partial GEMM over my k-window (W from registers) ----
      f32x4 acc0 = {0.f, 0.f, 0.f, 0.f};
      f32x4 acc1 = {0.f, 0.f, 0.f, 0.f};
#pragma unroll
      for (int ks = 0; ks < 4; ++ks) {
        int ia = (l15 * KD + kw + ks * 32 + grp * 8) ^ ((l15 & 7) << 3);
        short8 af = *reinterpret_cast<const short8*>(&Xl[p][ia]);
        acc0 = __builtin_amdgcn_mfma_f32_16x16x32_bf16(af, wb0[ks], acc0, 0, 0, 0);
        acc1 = __builtin_amdgcn_mfma_f32_16x16x32_bf16(af, wb1[ks], acc1, 0, 0, 0);
      }
      // ---- cross-wave k-combine via LDS scratch ----
      float* sw = &scratch[(wave * 64 + lane) * 8];
      *reinterpret_cast<f32x4*>(sw) = acc0;
      *reinterpret_cast<f32x4*>(sw + 4) = acc1;
      __syncthreads();
      f32x4 d0 = {0.f, 0.f, 0.f, 0.f};
      f32x4 d1 = {0.f, 0.f, 0.f, 0.f};
#pragma unroll
      for (int ww = 0; ww < 4; ++ww) {
        const float* sr = &scratch[(ww * 64 + lane) * 8];
        d0 += *reinterpret_cast<const f32x4*>(sr);
        d1 += *reinterpret_cast<const f32x4*>(sr + 4);
      }
      // per-chunk: just 4 fmax into the deferred-reduction registers
#pragma unroll
      for (int r = 0; r < 4; ++r) v[q][r] = fmaxf(d0[r], d1[r]);

      // ---- write next chunk's rows into the other buffer ----
      if (c < NCHUNK - 1) {
#pragma unroll
        for (int m = 0; m < 8; ++m) {
          int r = wave * 4 + (m >> 1);
          int k = (m & 1) * 256 + lane * 4;
          int iw = (r * KD + k) ^ ((r & 7) << 3);
          f32x4 hv = (m == 0) ? h0 : (m == 1) ? h1 : (m == 2) ? h2 : (m == 3) ? h3
                   : (m == 4) ? h4 : (m == 5) ? h5 : (m == 6) ? h6 : h7;
          *reinterpret_cast<s16x4*>(&Xl[p ^ 1][iw]) = cvt4(hv);
        }
        __syncthreads();
      }
    }
    // ---- flush: batched 64-row LSE over the 4 chunks (registers only) ----
#pragma unroll
    for (int mask = 1; mask < 16; mask <<= 1) {
#pragma unroll
      for (int q = 0; q < 4; ++q)
#pragma unroll
        for (int r = 0; r < 4; ++r)
          v[q][r] = fmaxf(v[q][r], __shfl_xor(v[q][r], mask));
    }
    float M = v[0][0];
#pragma unroll
    for (int q = 0; q < 4; ++q)
#pragma unroll
      for (int r = 0; r < 4; ++r) M = fmaxf(M, v[q][r]);
    M = fmaxf(M, __shfl_xor(M, 16));
    M = fmaxf(M, __shfl_xor(M, 32));
    float s = 0.0f;
#pragma unroll
    for (int q = 0; q < 4; ++q)
#pragma unroll
      for (int r = 0; r < 4; ++r) s += __expf(v[q][r] - M);
#pragma unroll
    for (int mask = 1; mask < 64; mask <<= 1) s += __shfl_xor(s, mask);
    s *= (1.0f / 16.0f);  // each row counted on its 16 l15 lanes
    float nM = fmaxf(runM, M);
    runS = runS * __expf(runM - nM) + s * __expf(M - nM);
    runM = nM;
  }

  // all 4 waves hold identical (runM, runS) after the combine
  if (tid == 0) {
    partial[2 * blockIdx.x] = runM;
    partial[2 * blockIdx.x + 1] = runS;
  }
}

// K2+K3 fused: each block redundantly reduces the 512 (max,sum) pairs
// (4 KB, L2/L3-resident) -> l2 scalar, then fills its 4 KB output slice.
__global__ __launch_bounds__(256) void k23_reduce_fill(const float* __restrict__ partial,
                                                       float* __restrict__ out) {
  const int tid = threadIdx.x;
  const int wave = tid >> 6;
  const int lane = tid & 63;
  float Ml[2], Sl[2];
  float m = -INFINITY;
#pragma unroll
  for (int j = 0; j < 2; ++j) {
    int i = tid + j * 256;
    Ml[j] = partial[2 * i];
    Sl[j] = partial[2 * i + 1];
    m = fmaxf(m, Ml[j]);
  }
#pragma unroll
  for (int mask = 1; mask < 64; mask <<= 1) m = fmaxf(m, __shfl_xor(m, mask));
  __shared__ float lm[4], lsum[4], vsh;
  if (lane == 0) lm[wave] = m;
  __syncthreads();
  float gM = fmaxf(fmaxf(lm[0], lm[1]), fmaxf(lm[2], lm[3]));
  float s = 0.0f;
#pragma unroll
  for (int j = 0; j < 2; ++j) s += Sl[j] * __expf(Ml[j] - gM);
#pragma unroll
  for (int mask = 1; mask < 64; mask <<= 1) s += __shfl_xor(s, mask);
  if (lane == 0) lsum[wave] = s;
  __syncthreads();
  if (tid == 0) {
    float S = lsum[0] + lsum[1] + lsum[2] + lsum[3];
    // l2 = l1 + log(B), B = 2^19
    vsh = gM + logf(S) + 19.0f * 0.69314718055994530942f;
  }
  __syncthreads();
  float v = vsh;
  size_t i = ((size_t)blockIdx.x * 256 + tid) * 4;
  f32x4 o = {v, v, v, v};
  *reinterpret_cast<f32x4*>(out + i) = o;
}

extern "C" void kernel_launch(void* const* d_in, const int* in_sizes, int n_in,
                              void* d_out, int out_size, void* d_ws, size_t ws_size,
                              hipStream_t stream) {
  const float* x = (const float*)d_in[0];
  const float* W = (const float*)d_in[1];
  float* out = (float*)d_out;
  float* ws = (float*)d_ws;

  k1_gemm_lse<<<NB1, 256, 0, stream>>>(x, W, ws);
  k23_reduce_fill<<<BATCH / 1024, 256, 0, stream>>>(ws, out);
}

// Round 14
// 161.341 us; speedup vs baseline: 1.0603x; 1.0214x over previous
//
#include <hip/hip_runtime.h>
#include <hip/hip_bf16.h>

typedef __attribute__((ext_vector_type(8))) short short8;
typedef __attribute__((ext_vector_type(4))) short s16x4;
typedef __attribute__((ext_vector_type(4))) float f32x4;

#define BATCH 524288
#define KD 512
#define OD 32
#define RPB 1024           // rows per block
#define NB1 (BATCH / RPB)  // 512 blocks = 2 blocks/CU resident
#define RPC 16             // rows per chunk
#define NCHUNK (RPB / RPC) // 64

__device__ __forceinline__ short bf16b(float f) {
  __hip_bfloat16 h = __float2bfloat16(f);
  return __builtin_bit_cast(short, h);
}
__device__ __forceinline__ s16x4 cvt4(f32x4 v) {
  s16x4 r;
  r[0] = bf16b(v[0]); r[1] = bf16b(v[1]);
  r[2] = bf16b(v[2]); r[3] = bf16b(v[3]);
  return r;
}
#define NTLOAD(p) __builtin_nontemporal_load(reinterpret_cast<const f32x4*>(p))

// K1: LDS-staged GEMM+LSE (best variant, round 10: 162.8 us, 6.85 TB/s read).
// Each wave's global reads are CONTIGUOUS 8 KB (4 consecutive rows x 2 KB)
// -> one DRAM-page stream per instruction, matching the fill/copy access
// shape. MFMA reads fragments from XOR-swizzled LDS; k-split 4x across
// waves; partials combined in LDS scratch.
__global__ __launch_bounds__(256, 2) void k1_gemm_lse(const float* __restrict__ x,
                                                      const float* __restrict__ W,
                                                      float* __restrict__ partial) {
  __shared__ __align__(16) short Wl[OD * KD];      // 32 KB, swizzled
  __shared__ __align__(16) short Xl[2][RPC * KD];  // 2 x 16 KB, swizzled
  __shared__ __align__(16) float scratch[4 * 64 * 8];  // 8 KB

  const int tid = threadIdx.x;
  const int wave = tid >> 6;
  const int lane = tid & 63;
  const int l15 = lane & 15;
  const int grp = lane >> 4;  // 0..3
  const size_t blockRow = (size_t)blockIdx.x * RPB;

  f32x4 h0, h1, h2, h3, h4, h5, h6, h7;  // staged x (4 rows x 2 instr)

  // ---- prologue: issue x loads for chunk 0, stage W, write chunk 0 ----
  {
    const float* gp = x + (blockRow + wave * 4) * KD + lane * 4;
    h0 = NTLOAD(gp);        h1 = NTLOAD(gp + 256);
    h2 = NTLOAD(gp + 512);  h3 = NTLOAD(gp + 768);
    h4 = NTLOAD(gp + 1024); h5 = NTLOAD(gp + 1280);
    h6 = NTLOAD(gp + 1536); h7 = NTLOAD(gp + 1792);
  }
#pragma unroll
  for (int j = 0; j < 16; ++j) {
    int e = tid + j * 256;          // float4 index, 4096 total
    f32x4 w = *reinterpret_cast<const f32x4*>(W + (size_t)e * 4);
    int o = e >> 7;                 // out-feature row
    int k = (e & 127) << 2;
    int iw = (o * KD + k) ^ ((o & 7) << 3);  // 16B-granule XOR swizzle
    *reinterpret_cast<s16x4*>(&Wl[iw]) = cvt4(w);
  }
  {
#pragma unroll
    for (int m = 0; m < 8; ++m) {
      int r = wave * 4 + (m >> 1);
      int k = (m & 1) * 256 + lane * 4;
      int iw = (r * KD + k) ^ ((r & 7) << 3);
      f32x4 hv = (m == 0) ? h0 : (m == 1) ? h1 : (m == 2) ? h2 : (m == 3) ? h3
               : (m == 4) ? h4 : (m == 5) ? h5 : (m == 6) ? h6 : h7;
      *reinterpret_cast<s16x4*>(&Xl[0][iw]) = cvt4(hv);
    }
  }
  __syncthreads();

  float runM = -INFINITY, runS = 0.0f;
  const int kw = wave * 128;  // this wave's k-window

  for (int c = 0; c < NCHUNK; ++c) {
    const int p = c & 1;
    if (c < NCHUNK - 1) {  // issue loads for next chunk (in flight during compute)
      const float* gp = x + (blockRow + (size_t)(c + 1) * RPC + wave * 4) * KD + lane * 4;
      h0 = NTLOAD(gp);        h1 = NTLOAD(gp + 256);
      h2 = NTLOAD(gp + 512);  h3 = NTLOAD(gp + 768);
      h4 = NTLOAD(gp + 1024); h5 = NTLOAD(gp + 1280);
      h6 = NTLOAD(gp + 1536); h7 = NTLOAD(gp + 1792);
    }
    // ---- compute partial GEMM over this wave's k-window ----
    f32x4 acc0 = {0.f, 0.f, 0.f, 0.f};
    f32x4 acc1 = {0.f, 0.f, 0.f, 0.f};
#pragma unroll
    for (int ks = 0; ks < 4; ++ks) {
      int k0 = kw + ks * 32;
      int ia = (l15 * KD + k0 + grp * 8) ^ ((l15 & 7) << 3);
      short8 af = *reinterpret_cast<const short8*>(&Xl[p][ia]);
      short8 b0 = *reinterpret_cast<const short8*>(&Wl[ia]);  // W row l15, same swz
      int ib1 = ((16 + l15) * KD + k0 + grp * 8) ^ ((l15 & 7) << 3);
      short8 b1 = *reinterpret_cast<const short8*>(&Wl[ib1]);
      acc0 = __builtin_amdgcn_mfma_f32_16x16x32_bf16(af, b0, acc0, 0, 0, 0);
      acc1 = __builtin_amdgcn_mfma_f32_16x16x32_bf16(af, b1, acc1, 0, 0, 0);
    }
    // ---- cross-wave k-combine via LDS scratch ----
    float* sw = &scratch[(wave * 64 + lane) * 8];
    *reinterpret_cast<f32x4*>(sw) = acc0;
    *reinterpret_cast<f32x4*>(sw + 4) = acc1;
    __syncthreads();
    f32x4 d0 = {0.f, 0.f, 0.f, 0.f};
    f32x4 d1 = {0.f, 0.f, 0.f, 0.f};
#pragma unroll
    for (int ww = 0; ww < 4; ++ww) {
      const float* sr = &scratch[(ww * 64 + lane) * 8];
      d0 += *reinterpret_cast<const f32x4*>(sr);
      d1 += *reinterpret_cast<const f32x4*>(sr + 4);
    }
    // ---- rowmax + per-chunk LSE, online merge ----
    // D layout: lane holds D[grp*4 + r][l15] (d0: outs 0-15, d1: outs 16-31)
    float v0 = fmaxf(d0[0], d1[0]);
    float v1 = fmaxf(d0[1], d1[1]);
    float v2 = fmaxf(d0[2], d1[2]);
    float v3 = fmaxf(d0[3], d1[3]);
#pragma unroll
    for (int mask = 1; mask < 16; mask <<= 1) {
      v0 = fmaxf(v0, __shfl_xor(v0, mask));
      v1 = fmaxf(v1, __shfl_xor(v1, mask));
      v2 = fmaxf(v2, __shfl_xor(v2, mask));
      v3 = fmaxf(v3, __shfl_xor(v3, mask));
    }
    float tmax = fmaxf(fmaxf(v0, v1), fmaxf(v2, v3));
    float wmax = fmaxf(tmax, __shfl_xor(tmax, 16));
    wmax = fmaxf(wmax, __shfl_xor(wmax, 32));
    float s = __expf(v0 - wmax) + __expf(v1 - wmax) +
              __expf(v2 - wmax) + __expf(v3 - wmax);
#pragma unroll
    for (int mask = 1; mask < 64; mask <<= 1) s += __shfl_xor(s, mask);
    s *= (1.0f / 16.0f);  // each row counted on its 16 l15 lanes
    float nM = fmaxf(runM, wmax);
    runS = runS * __expf(runM - nM) + s * __expf(wmax - nM);
    runM = nM;

    // ---- write next chunk's staged rows (loads arrived under compute) ----
    if (c < NCHUNK - 1) {
#pragma unroll
      for (int m = 0; m < 8; ++m) {
        int r = wave * 4 + (m >> 1);
        int k = (m & 1) * 256 + lane * 4;
        int iw = (r * KD + k) ^ ((r & 7) << 3);
        f32x4 hv = (m == 0) ? h0 : (m == 1) ? h1 : (m == 2) ? h2 : (m == 3) ? h3
                 : (m == 4) ? h4 : (m == 5) ? h5 : (m == 6) ? h6 : h7;
        *reinterpret_cast<s16x4*>(&Xl[p ^ 1][iw]) = cvt4(hv);
      }
      __syncthreads();
    }
  }

  if (tid == 0) {  // all waves hold identical (runM, runS)
    partial[2 * blockIdx.x] = runM;
    partial[2 * blockIdx.x + 1] = runS;
  }
}

// K2+K3 fused: each block redundantly reduces the 512 (max,sum) pairs
// (4 KB, L2/L3-resident) -> l2 scalar, then fills its 4 KB output slice.
__global__ __launch_bounds__(256) void k23_reduce_fill(const float* __restrict__ partial,
                                                       float* __restrict__ out) {
  const int tid = threadIdx.x;
  const int wave = tid >> 6;
  const int lane = tid & 63;
  float Ml[2], Sl[2];
  float m = -INFINITY;
#pragma unroll
  for (int j = 0; j < 2; ++j) {
    int i = tid + j * 256;
    Ml[j] = partial[2 * i];
    Sl[j] = partial[2 * i + 1];
    m = fmaxf(m, Ml[j]);
  }
#pragma unroll
  for (int mask = 1; mask < 64; mask <<= 1) m = fmaxf(m, __shfl_xor(m, mask));
  __shared__ float lm[4], lsum[4], vsh;
  if (lane == 0) lm[wave] = m;
  __syncthreads();
  float gM = fmaxf(fmaxf(lm[0], lm[1]), fmaxf(lm[2], lm[3]));
  float s = 0.0f;
#pragma unroll
  for (int j = 0; j < 2; ++j) s += Sl[j] * __expf(Ml[j] - gM);
#pragma unroll
  for (int mask = 1; mask < 64; mask <<= 1) s += __shfl_xor(s, mask);
  if (lane == 0) lsum[wave] = s;
  __syncthreads();
  if (tid == 0) {
    float S = lsum[0] + lsum[1] + lsum[2] + lsum[3];
    // l2 = l1 + log(B), B = 2^19
    vsh = gM + logf(S) + 19.0f * 0.69314718055994530942f;
  }
  __syncthreads();
  float v = vsh;
  size_t i = ((size_t)blockIdx.x * 256 + tid) * 4;
  f32x4 o = {v, v, v, v};
  *reinterpret_cast<f32x4*>(out + i) = o;
}

extern "C" void kernel_launch(void* const* d_in, const int* in_sizes, int n_in,
                              void* d_out, int out_size, void* d_ws, size_t ws_size,
                              hipStream_t stream) {
  const float* x = (const float*)d_in[0];
  const float* W = (const float*)d_in[1];
  float* out = (float*)d_out;
  float* ws = (float*)d_ws;

  k1_gemm_lse<<<NB1, 256, 0, stream>>>(x, W, ws);
  k23_reduce_fill<<<BATCH / 1024, 256, 0, stream>>>(ws, out);
}